// Round 2
// baseline (264.368 us; speedup 1.0000x reference)
//
#include <hip/hip_runtime.h>
#include <stdint.h>

typedef short bf16x8 __attribute__((ext_vector_type(8)));
typedef float f32x4 __attribute__((ext_vector_type(4)));

#define MFMA16(a,b,c) __builtin_amdgcn_mfma_f32_16x16x32_bf16((a),(b),(c),0,0,0)

static __device__ __forceinline__ unsigned short f2bf(float f){
  union { float f; unsigned int u; } v; v.f = f;
  unsigned int r = (v.u + 0x7fffu + ((v.u >> 16) & 1u)) >> 16;
  return (unsigned short)r;
}

static __device__ __forceinline__ void gload16(const void* g, void* l){
  __builtin_amdgcn_global_load_lds((const __attribute__((address_space(1))) void*)g,
                                   (__attribute__((address_space(3))) void*)l, 16, 0, 0);
}

#define NB 2
#define NS 4096
#define ND 1024
#define NROWS 8192

// workspace byte offsets
#define XB_OFF    0u
#define WT_OFF    16777216u
#define QKVF_OFF  17563648u
#define QKVB_OFF  30146560u
#define STATS_OFF 42729472u

// ---------------- prep: x (fp32) -> xb (bf16) ----------------
__global__ void k_prep_x(const float4* __restrict__ x4, uint4* __restrict__ xb4){
  int idx = blockIdx.x * 256 + threadIdx.x;
  float4 a = x4[idx*2], b = x4[idx*2+1];
  uint4 o;
  o.x = (unsigned)f2bf(a.x) | ((unsigned)f2bf(a.y) << 16);
  o.y = (unsigned)f2bf(a.z) | ((unsigned)f2bf(a.w) << 16);
  o.z = (unsigned)f2bf(b.x) | ((unsigned)f2bf(b.y) << 16);
  o.w = (unsigned)f2bf(b.z) | ((unsigned)f2bf(b.w) << 16);
  xb4[idx] = o;
}

// ---------------- prep: Wq/Wk/Wv [1024][128] fp32 -> Wt [384][1024] bf16 (transposed) ----------------
__global__ void k_prep_w(const float* __restrict__ Wq, const float* __restrict__ Wk,
                         const float* __restrict__ Wv, unsigned short* __restrict__ Wt){
  int idx = blockIdx.x * 256 + threadIdx.x;      // 393,216
  int m = idx >> 17;
  int r = idx & 131071;
  int n = r >> 10;
  int k = r & 1023;
  const float* W = (m == 0) ? Wq : (m == 1 ? Wk : Wv);
  Wt[idx] = f2bf(W[k*128 + n]);
}

// ---------------- GEMM (m97-style): xb[8192][1024] @ Wt^T -> QKVf [3][8192][128] fp32 ----------------
__global__ __launch_bounds__(256,4)
void k_gemm_qkv(const unsigned short* __restrict__ xb,
                const unsigned short* __restrict__ Wt,
                float* __restrict__ QKVf){
  __shared__ __align__(16) unsigned short As[2048];   // [64 rows][32 k] linear
  __shared__ __align__(16) unsigned short Bs[2048];
  int bx = blockIdx.x;
  int m0 = (bx & 127) << 6;
  int n0 = (bx >> 7) << 6;
  int t = threadIdx.x;
  int lane = t & 63, w = t >> 6;
  int lq = lane & 15, g = lane >> 4;
  f32x4 acc[4];
  #pragma unroll
  for (int mi = 0; mi < 4; ++mi) acc[mi] = f32x4{0.f,0.f,0.f,0.f};

  const unsigned short* src = (w < 2) ? xb : Wt;
  int tile0 = (w < 2) ? m0 : n0;
  unsigned short* dstbase = (w < 2) ? As : Bs;
  int oa0 = (w & 1) * 2;
  int row_l = lane >> 2;          // 0..15
  int col_l = (lane & 3) * 8;     // 0,8,16,24

  for (int k0 = 0; k0 < 1024; k0 += 32){
    #pragma unroll
    for (int i = 0; i < 2; ++i){
      int oa = oa0 + i;
      gload16(src + (size_t)(tile0 + oa*16 + row_l)*1024 + k0 + col_l,
              dstbase + oa*512);
    }
    __syncthreads();
    bf16x8 bfr = *(const bf16x8*)(Bs + (w*16 + lq)*32 + g*8);
    #pragma unroll
    for (int mi = 0; mi < 4; ++mi){
      bf16x8 afr = *(const bf16x8*)(As + (mi*16 + lq)*32 + g*8);
      acc[mi] = MFMA16(afr, bfr, acc[mi]);
    }
    __syncthreads();
  }
  int ncol = n0 + w*16 + lq;
  int mat = ncol >> 7, c = ncol & 127;
  float* op = QKVf + (size_t)mat*NROWS*128 + c;
  #pragma unroll
  for (int mi = 0; mi < 4; ++mi){
    int rbase = m0 + mi*16 + 4*g;
    #pragma unroll
    for (int r = 0; r < 4; ++r)
      op[(size_t)(rbase + r)*128] = acc[mi][r];
  }
}

// ---------------- RoPE + bf16 convert; Q pre-scaled by 1/8 ----------------
__global__ void k_rope(const float* __restrict__ QKVf, unsigned short* __restrict__ QKVb){
  int idx = blockIdx.x * 256 + threadIdx.x;   // 524,288
  int row = idx >> 6, i = idx & 63;
  int s = row & 4095;
  double inv = exp((double)i * -0.14391156831212805);   // ln(10000)/64
  double ang = (double)s * inv;
  float cf = (float)cos(ang), sf = (float)sin(ang);
  const float* Qf = QKVf;
  const float* Kf = QKVf + (size_t)NROWS*128;
  const float* Vf = QKVf + (size_t)2*NROWS*128;
  size_t base = (size_t)row * 128;
  float q1 = Qf[base+i], q2 = Qf[base+i+64];
  float k1 = Kf[base+i], k2 = Kf[base+i+64];
  float v1 = Vf[base+i], v2 = Vf[base+i+64];
  unsigned short* Qb = QKVb;
  unsigned short* Kb = QKVb + (size_t)NROWS*128;
  unsigned short* Vb = QKVb + (size_t)2*NROWS*128;
  Qb[base+i]    = f2bf((q1*cf - q2*sf) * 0.125f);
  Qb[base+i+64] = f2bf((q2*cf + q1*sf) * 0.125f);
  Kb[base+i]    = f2bf(k1*cf - k2*sf);
  Kb[base+i+64] = f2bf(k2*cf + k1*sf);
  Vb[base+i]    = f2bf(v1);
  Vb[base+i+64] = f2bf(v2);
}

// ---------------- pass A: per-row softmax stats (m, l) for both mats ----------------
// grid 1024 = b(2) x qt(256) x kh(2); 4 waves x 512 keys each; partial stats out.
__global__ __launch_bounds__(256,4)
void k_stats(const unsigned short* __restrict__ QKVb, float* __restrict__ stats){
  int bid = blockIdx.x;
  int b = bid >> 9, qt = (bid >> 1) & 255, kh = bid & 1;
  int q0 = qt << 4;
  int t = threadIdx.x;
  int w = t >> 6, lane = t & 63;
  int lq = lane & 15, g = lane >> 4;
  const uint4* Qb4 = (const uint4*)QKVb;
  const uint4* Kb4 = (const uint4*)(QKVb + (size_t)NROWS*128);
  size_t rowbase = (size_t)b * 4096;

  bf16x8 qf[4];
  #pragma unroll
  for (int f = 0; f < 4; ++f){
    uint4 v = Qb4[(rowbase + q0 + lq)*16 + 4*f + g];
    qf[f] = *(bf16x8*)&v;
  }
  int key0 = kh*2048 + w*512;
  float m1 = -1e30f, m2 = -1e30f, s1 = 0.f, s2 = 0.f;

  bf16x8 kf[2][4];
  #pragma unroll
  for (int h = 0; h < 2; ++h)
    #pragma unroll
    for (int f = 0; f < 4; ++f){
      uint4 v = Kb4[(rowbase + key0 + h*16 + lq)*16 + 4*f + g];
      kf[h][f] = *(bf16x8*)&v;
    }

  for (int it = 0; it < 16; ++it){
    f32x4 S1[2], S2[2];
    #pragma unroll
    for (int h = 0; h < 2; ++h){
      f32x4 z1 = f32x4{0.f,0.f,0.f,0.f};
      z1 = MFMA16(kf[h][0], qf[0], z1);
      S1[h] = MFMA16(kf[h][1], qf[1], z1);
      f32x4 z2 = f32x4{0.f,0.f,0.f,0.f};
      z2 = MFMA16(kf[h][2], qf[2], z2);
      S2[h] = MFMA16(kf[h][3], qf[3], z2);
    }
    if (it < 15){
      int k0 = key0 + (it+1)*32;
      #pragma unroll
      for (int h = 0; h < 2; ++h)
        #pragma unroll
        for (int f = 0; f < 4; ++f){
          uint4 v = Kb4[(rowbase + k0 + h*16 + lq)*16 + 4*f + g];
          kf[h][f] = *(bf16x8*)&v;
        }
    }
    float t1 = fmaxf(fmaxf(fmaxf(S1[0][0],S1[0][1]), fmaxf(S1[0][2],S1[0][3])),
                     fmaxf(fmaxf(S1[1][0],S1[1][1]), fmaxf(S1[1][2],S1[1][3])));
    float t2 = fmaxf(fmaxf(fmaxf(S2[0][0],S2[0][1]), fmaxf(S2[0][2],S2[0][3])),
                     fmaxf(fmaxf(S2[1][0],S2[1][1]), fmaxf(S2[1][2],S2[1][3])));
    t1 = fmaxf(t1, __shfl_xor(t1, 16)); t1 = fmaxf(t1, __shfl_xor(t1, 32));
    t2 = fmaxf(t2, __shfl_xor(t2, 16)); t2 = fmaxf(t2, __shfl_xor(t2, 32));
    float mn1 = fmaxf(m1, t1), mn2 = fmaxf(m2, t2);
    float p1 = 0.f, p2 = 0.f;
    #pragma unroll
    for (int h = 0; h < 2; ++h)
      #pragma unroll
      for (int r = 0; r < 4; ++r){
        p1 += __expf(S1[h][r] - mn1);
        p2 += __expf(S2[h][r] - mn2);
      }
    p1 += __shfl_xor(p1, 16); p1 += __shfl_xor(p1, 32);
    p2 += __shfl_xor(p2, 16); p2 += __shfl_xor(p2, 32);
    s1 = s1 * __expf(m1 - mn1) + p1; m1 = mn1;
    s2 = s2 * __expf(m2 - mn2) + p2; m2 = mn2;
  }
  if (lane < 16){
    int wu = kh*4 + w;
    size_t bqt = (size_t)b*256 + qt;
    *(float4*)&stats[((bqt*8 + wu)*16 + lq)*4] = float4{m1, s1, m2, s2};
  }
}

// ---------------- pass B: combined-weight PV, single accumulator ----------------
// grid 512 = b(2) x qt(256); 8 waves x 512 keys; sum-combine.
__global__ __launch_bounds__(512,4)
void k_attnB(const unsigned short* __restrict__ QKVb,
             const float* __restrict__ lq1, const float* __restrict__ lq2,
             const float* __restrict__ lk1, const float* __restrict__ lk2,
             const float* __restrict__ stats, float* __restrict__ out){
  __shared__ __align__(16) char lds[65536];   // 8 waves x 8KB V tiles; reused as combine buf
  int bid = blockIdx.x;
  int b = bid >> 8, qt = bid & 255;
  int q0 = qt << 4;
  int t = threadIdx.x;
  int w = t >> 6, lane = t & 63;
  int lq = lane & 15, g = lane >> 4;
  const uint4* Qb4 = (const uint4*)QKVb;
  const uint4* Kb4 = (const uint4*)(QKVb + (size_t)NROWS*128);
  const unsigned short* Vb = QKVb + (size_t)2*NROWS*128;
  size_t rowbase = (size_t)b * 4096;

  // lambda (shfl reduce over 64 lanes)
  float pp1 = lq1[lane]*lk1[lane], pp2 = lq2[lane]*lk2[lane];
  #pragma unroll
  for (int d = 1; d < 64; d <<= 1){ pp1 += __shfl_xor(pp1, d); pp2 += __shfl_xor(pp2, d); }
  float lam = __expf(pp1) - __expf(pp2) + 0.3555090675909693f;

  // stats -> a1, a2 for this lane's q = lq
  size_t bqt = (size_t)b*256 + qt;
  float M1 = -1e30f, M2 = -1e30f;
  float4 st[8];
  #pragma unroll
  for (int wu = 0; wu < 8; ++wu){
    st[wu] = *(const float4*)&stats[((bqt*8 + wu)*16 + lq)*4];
    M1 = fmaxf(M1, st[wu].x); M2 = fmaxf(M2, st[wu].z);
  }
  float L1 = 0.f, L2 = 0.f;
  #pragma unroll
  for (int wu = 0; wu < 8; ++wu){
    L1 += st[wu].y * __expf(st[wu].x - M1);
    L2 += st[wu].w * __expf(st[wu].z - M2);
  }
  float a1 = M1 + __logf(L1);
  float a2 = M2 + __logf(L2);

  bf16x8 qf[4];
  #pragma unroll
  for (int f = 0; f < 4; ++f){
    uint4 v = Qb4[(rowbase + q0 + lq)*16 + 4*f + g];
    qf[f] = *(bf16x8*)&v;
  }
  f32x4 O[8];
  #pragma unroll
  for (int dg = 0; dg < 8; ++dg) O[dg] = f32x4{0.f,0.f,0.f,0.f};

  char* vlds = lds + w*8192;
  unsigned vbase = (unsigned)(uintptr_t)vlds;
  int key0 = w << 9;
  // V staging: LDS linear dest (gload_lds), pre-swizzled per-lane global source.
  // LDS byte b: k=((b>>7)&7)*4+((b>>5)&3), d=(b>>10)*16+((b>>1)&15)  (tr_b16 subtile layout)
  int kl = ((lane >> 3) & 7)*4 + ((lane >> 1) & 3);
  int dl = 8*(lane & 1);
  const unsigned short* vsrc = Vb + (rowbase + key0 + kl)*128 + dl;

  bf16x8 kf[2][4];
  #pragma unroll
  for (int h = 0; h < 2; ++h)
    #pragma unroll
    for (int f = 0; f < 4; ++f){
      uint4 v = Kb4[(rowbase + key0 + h*16 + lq)*16 + 4*f + g];
      kf[h][f] = *(bf16x8*)&v;
    }
  #pragma unroll
  for (int dg = 0; dg < 8; ++dg)
    gload16(vsrc + dg*16, vlds + dg*1024);

  for (int it = 0; it < 16; ++it){
    int k0 = key0 + it*32;
    f32x4 S1[2], S2[2];
    #pragma unroll
    for (int h = 0; h < 2; ++h){
      f32x4 z1 = f32x4{0.f,0.f,0.f,0.f};
      z1 = MFMA16(kf[h][0], qf[0], z1);
      S1[h] = MFMA16(kf[h][1], qf[1], z1);
      f32x4 z2 = f32x4{0.f,0.f,0.f,0.f};
      z2 = MFMA16(kf[h][2], qf[2], z2);
      S2[h] = MFMA16(kf[h][3], qf[3], z2);
    }
    // combined final weights: P = exp(S1-a1) - lam*exp(S2-a2)
    bf16x8 P;
    #pragma unroll
    for (int h = 0; h < 2; ++h)
      #pragma unroll
      for (int r = 0; r < 4; ++r){
        float p = fmaf(-lam, __expf(S2[h][r] - a2), __expf(S1[h][r] - a1));
        P[h*4 + r] = (short)f2bf(p);
      }
    // V(it) staged?
    asm volatile("s_waitcnt vmcnt(0)" ::: "memory");
    unsigned long long tr0[4], tr1[4];
    #pragma unroll
    for (int dg = 0; dg < 4; ++dg){
      unsigned a = vbase + dg*1024 + lane*8;
      asm volatile("ds_read_b64_tr_b16 %0, %2 offset:0\n\t"
                   "ds_read_b64_tr_b16 %1, %2 offset:512"
                   : "=&v"(tr0[dg]), "=&v"(tr1[dg]) : "v"(a) : "memory");
    }
    asm volatile("s_waitcnt lgkmcnt(0)" ::: "memory");
    __builtin_amdgcn_sched_barrier(0);
    if (it < 15){
      int kn = k0 + 32;
      #pragma unroll
      for (int h = 0; h < 2; ++h)
        #pragma unroll
        for (int f = 0; f < 4; ++f){
          uint4 v = Kb4[(rowbase + kn + h*16 + lq)*16 + 4*f + g];
          kf[h][f] = *(bf16x8*)&v;
        }
    }
    #pragma unroll
    for (int dg = 0; dg < 4; ++dg){
      union { unsigned long long u[2]; bf16x8 v; } vv;
      vv.u[0] = tr0[dg]; vv.u[1] = tr1[dg];
      O[dg] = MFMA16(P, vv.v, O[dg]);
    }
    #pragma unroll
    for (int dg = 4; dg < 8; ++dg){
      unsigned a = vbase + dg*1024 + lane*8;
      asm volatile("ds_read_b64_tr_b16 %0, %2 offset:0\n\t"
                   "ds_read_b64_tr_b16 %1, %2 offset:512"
                   : "=&v"(tr0[dg-4]), "=&v"(tr1[dg-4]) : "v"(a) : "memory");
    }
    asm volatile("s_waitcnt lgkmcnt(0)" ::: "memory");
    __builtin_amdgcn_sched_barrier(0);
    if (it < 15){
      const unsigned short* vs = vsrc + (size_t)(it+1)*32*128;
      #pragma unroll
      for (int dg = 0; dg < 8; ++dg)
        gload16(vs + dg*16, vlds + dg*1024);
    }
    #pragma unroll
    for (int dg = 4; dg < 8; ++dg){
      union { unsigned long long u[2]; bf16x8 v; } vv;
      vv.u[0] = tr0[dg-4]; vv.u[1] = tr1[dg-4];
      O[dg] = MFMA16(P, vv.v, O[dg]);
    }
  }

  // ---- cross-wave sum combine (P already normalized), 2 phases of 32KB ----
  float* cbuf = (float*)lds;
  #pragma unroll
  for (int ph = 0; ph < 2; ++ph){
    __syncthreads();
    #pragma unroll
    for (int dgl = 0; dgl < 4; ++dgl){
      #pragma unroll
      for (int r = 0; r < 4; ++r)
        cbuf[((4*g + r)*8 + w)*64 + dgl*16 + lq] = O[ph*4 + dgl][r];
    }
    __syncthreads();
    int q = t >> 5, i2 = t & 31;
    const float2* c2 = (const float2*)cbuf;
    float2 acc = c2[(q*8 + 0)*32 + i2];
    #pragma unroll
    for (int wu = 1; wu < 8; ++wu){
      float2 v = c2[(q*8 + wu)*32 + i2];
      acc.x += v.x; acc.y += v.y;
    }
    *(float2*)&out[(rowbase + q0 + q)*128 + ph*64 + 2*i2] = acc;
  }
}

extern "C" void kernel_launch(void* const* d_in, const int* in_sizes, int n_in,
                              void* d_out, int out_size, void* d_ws, size_t ws_size,
                              hipStream_t stream){
  const float* x   = (const float*)d_in[0];
  const float* Wq  = (const float*)d_in[1];
  const float* Wk  = (const float*)d_in[2];
  const float* Wv  = (const float*)d_in[3];
  const float* lq1 = (const float*)d_in[4];
  const float* lq2 = (const float*)d_in[5];
  const float* lk1 = (const float*)d_in[6];
  const float* lk2 = (const float*)d_in[7];
  float* out = (float*)d_out;
  char* ws = (char*)d_ws;

  unsigned short* xb    = (unsigned short*)(ws + XB_OFF);
  unsigned short* Wt    = (unsigned short*)(ws + WT_OFF);
  float*          QKVf  = (float*)(ws + QKVF_OFF);
  unsigned short* QKVb  = (unsigned short*)(ws + QKVB_OFF);
  float*          stats = (float*)(ws + STATS_OFF);

  k_prep_x<<<dim3(4096), dim3(256), 0, stream>>>((const float4*)x, (uint4*)xb);
  k_prep_w<<<dim3(1536), dim3(256), 0, stream>>>(Wq, Wk, Wv, Wt);
  k_gemm_qkv<<<dim3(768), dim3(256), 0, stream>>>(xb, Wt, QKVf);
  k_rope<<<dim3(2048), dim3(256), 0, stream>>>(QKVf, QKVb);
  k_stats<<<dim3(1024), dim3(256), 0, stream>>>(QKVb, stats);
  k_attnB<<<dim3(512), dim3(512), 0, stream>>>(QKVb, lq1, lq2, lk1, lk2, stats, out);
}

// Round 3
// 173.746 us; speedup vs baseline: 1.5216x; 1.5216x over previous
//
#include <hip/hip_runtime.h>
#include <stdint.h>

typedef short bf16x8 __attribute__((ext_vector_type(8)));
typedef float f32x4 __attribute__((ext_vector_type(4)));

#define MFMA16(a,b,c) __builtin_amdgcn_mfma_f32_16x16x32_bf16((a),(b),(c),0,0,0)

static __device__ __forceinline__ unsigned short f2bf(float f){
  union { float f; unsigned int u; } v; v.f = f;
  unsigned int r = (v.u + 0x7fffu + ((v.u >> 16) & 1u)) >> 16;
  return (unsigned short)r;
}

static __device__ __forceinline__ void gload16(const void* g, void* l){
  __builtin_amdgcn_global_load_lds((const __attribute__((address_space(1))) void*)g,
                                   (__attribute__((address_space(3))) void*)l, 16, 0, 0);
}

#define NB 2
#define NS 4096
#define NROWS 8192

// workspace byte offsets
#define XB_OFF    0u
#define WT_OFF    16777216u
#define QKVF_OFF  17563648u
#define QKVB_OFF  30146560u
#define STATS_OFF 36438016u
#define OP7_OFF   37486592u
// O partials: ks 0..6 at ws + ks*4MB (dead xb/Wt/QKVf), ks 7 at OP7_OFF. Max ws use 41.7MB.

// ---------------- prep: x (fp32) -> xb (bf16) ----------------
__global__ void k_prep_x(const float4* __restrict__ x4, uint4* __restrict__ xb4){
  int idx = blockIdx.x * 256 + threadIdx.x;
  float4 a = x4[idx*2], b = x4[idx*2+1];
  uint4 o;
  o.x = (unsigned)f2bf(a.x) | ((unsigned)f2bf(a.y) << 16);
  o.y = (unsigned)f2bf(a.z) | ((unsigned)f2bf(a.w) << 16);
  o.z = (unsigned)f2bf(b.x) | ((unsigned)f2bf(b.y) << 16);
  o.w = (unsigned)f2bf(b.z) | ((unsigned)f2bf(b.w) << 16);
  xb4[idx] = o;
}

// ---------------- prep W: LDS transpose, [1024][128]f32 x3 -> Wt[384][1024] bf16 ----------------
__global__ void k_prep_w(const float* __restrict__ Wq, const float* __restrict__ Wk,
                         const float* __restrict__ Wv, unsigned short* __restrict__ Wt){
  __shared__ float Wl[64][65];
  int bx = blockIdx.x;               // 96 = 6 n-tiles x 16 k-tiles
  int nt = bx / 16, kt = bx % 16;
  int n0 = nt*64, k0 = kt*64;
  int mat = n0 >> 7, nl0 = n0 & 127;
  const float* W = (mat == 0) ? Wq : (mat == 1 ? Wk : Wv);
  int t = threadIdx.x;
  int tr = t >> 4, tc = (t & 15) * 4;
  #pragma unroll
  for (int i = 0; i < 4; ++i){
    int kk = i*16 + tr;
    float4 v = *(const float4*)&W[(size_t)(k0+kk)*128 + nl0 + tc];
    Wl[kk][tc] = v.x; Wl[kk][tc+1] = v.y; Wl[kk][tc+2] = v.z; Wl[kk][tc+3] = v.w;
  }
  __syncthreads();
  int nn = t >> 2, kk0 = (t & 3) * 16;
  unsigned short tmp[16];
  #pragma unroll
  for (int j = 0; j < 16; ++j) tmp[j] = f2bf(Wl[kk0+j][nn]);
  *(uint4*)&Wt[(size_t)(n0+nn)*1024 + k0 + kk0]     = *(uint4*)&tmp[0];
  *(uint4*)&Wt[(size_t)(n0+nn)*1024 + k0 + kk0 + 8] = *(uint4*)&tmp[8];
}

// ---------------- GEMM: xb[8192][1024] @ Wt^T -> QKVf[3][8192][128] f32 ----------------
// 64x64 tile, BK=64, double-buffered gload_lds, XOR-swizzled LDS.
__global__ __launch_bounds__(256,4)
void k_gemm_qkv(const unsigned short* __restrict__ xb,
                const unsigned short* __restrict__ Wt,
                float* __restrict__ QKVf){
  __shared__ __align__(16) char As[2][8192];
  __shared__ __align__(16) char Bs[2][8192];
  int hw = blockIdx.x;
  int bx = (hw & 7)*96 + (hw >> 3);     // XCD chunking (768 % 8 == 0)
  int m0 = (bx & 127) << 6;
  int n0 = (bx >> 7) << 6;
  int t = threadIdx.x, lane = t & 63, w = t >> 6;
  int lq = lane & 15, g = lane >> 4;
  f32x4 acc[4];
  #pragma unroll
  for (int mi = 0; mi < 4; ++mi) acc[mi] = f32x4{0.f,0.f,0.f,0.f};

  int row_l = w*16 + (lane >> 3);                 // + i*8
  int chunk = ((lane & 7) ^ (lane >> 3)) << 4;    // pre-swizzled source chunk
  const char* asrc = (const char*)(xb + (size_t)(m0 + row_l)*1024) + chunk;
  const char* bsrc = (const char*)(Wt + (size_t)(n0 + row_l)*1024) + chunk;

  int buf = 0;
  #pragma unroll
  for (int i = 0; i < 2; ++i){
    gload16(asrc + (size_t)i*16384, As[0] + w*2048 + i*1024);
    gload16(bsrc + (size_t)i*16384, Bs[0] + w*2048 + i*1024);
  }
  __syncthreads();

  for (int kk = 0; kk < 16; ++kk){
    if (kk < 15){
      size_t ko = (size_t)(kk+1)*128;   // bytes: 64 k * 2B
      #pragma unroll
      for (int i = 0; i < 2; ++i){
        gload16(asrc + ko + (size_t)i*16384, As[buf^1] + w*2048 + i*1024);
        gload16(bsrc + ko + (size_t)i*16384, Bs[buf^1] + w*2048 + i*1024);
      }
    }
    int xo = (lq & 7);
    bf16x8 bfr[2], afr[4][2];
    #pragma unroll
    for (int s = 0; s < 2; ++s)
      bfr[s] = *(const bf16x8*)(Bs[buf] + (w*16+lq)*128 + (((s*4+g) ^ xo) << 4));
    #pragma unroll
    for (int mi = 0; mi < 4; ++mi)
      #pragma unroll
      for (int s = 0; s < 2; ++s)
        afr[mi][s] = *(const bf16x8*)(As[buf] + (mi*16+lq)*128 + (((s*4+g) ^ xo) << 4));
    #pragma unroll
    for (int mi = 0; mi < 4; ++mi)
      #pragma unroll
      for (int s = 0; s < 2; ++s)
        acc[mi] = MFMA16(afr[mi][s], bfr[s], acc[mi]);
    __syncthreads();
    buf ^= 1;
  }
  int ncol = n0 + w*16 + lq;
  int mat = ncol >> 7, c = ncol & 127;
  float* op = QKVf + (size_t)mat*NROWS*128 + c;
  #pragma unroll
  for (int mi = 0; mi < 4; ++mi){
    int rbase = m0 + mi*16 + 4*g;
    #pragma unroll
    for (int r = 0; r < 4; ++r)
      op[(size_t)(rbase + r)*128] = acc[mi][r];
  }
}

// ---------------- RoPE + bf16; Q pre-scaled 1/8; f64 angle + f32 HW sincos ----------------
__global__ void k_rope(const float* __restrict__ QKVf, unsigned short* __restrict__ QKVb){
  int idx = blockIdx.x * 256 + threadIdx.x;   // 524,288
  int row = idx >> 6, i = idx & 63;
  int s = row & 4095;
  double inv = exp((double)i * -0.14391156831212805);   // ln(10000)/64
  double rev = (double)s * inv * 0.15915494309189535;   // angle in revolutions
  rev -= floor(rev);
  float fr = (float)rev;
  float cf, sf;
  asm("v_cos_f32 %0, %1" : "=v"(cf) : "v"(fr));
  asm("v_sin_f32 %0, %1" : "=v"(sf) : "v"(fr));
  const float* Qf = QKVf;
  const float* Kf = QKVf + (size_t)NROWS*128;
  const float* Vf = QKVf + (size_t)2*NROWS*128;
  size_t base = (size_t)row * 128;
  float q1 = Qf[base+i], q2 = Qf[base+i+64];
  float k1 = Kf[base+i], k2 = Kf[base+i+64];
  float v1 = Vf[base+i], v2 = Vf[base+i+64];
  unsigned short* Qb = QKVb;
  unsigned short* Kb = QKVb + (size_t)NROWS*128;
  unsigned short* Vb = QKVb + (size_t)2*NROWS*128;
  Qb[base+i]    = f2bf((q1*cf - q2*sf) * 0.125f);
  Qb[base+i+64] = f2bf((q2*cf + q1*sf) * 0.125f);
  Kb[base+i]    = f2bf(k1*cf - k2*sf);
  Kb[base+i+64] = f2bf(k2*cf + k1*sf);
  Vb[base+i]    = f2bf(v1);
  Vb[base+i+64] = f2bf(v2);
}

// ---------------- pass A: per-row (m,l) stats. 128 q-rows/block, K shared in LDS ----------------
// grid 512 = b(2) x ks(8) x qt(32); 8 waves x 16 q-rows; 512 keys/block, 16 steps of 32.
__global__ __launch_bounds__(512,4)
void k_stats(const unsigned short* __restrict__ QKVb, float* __restrict__ stats){
  __shared__ __align__(16) char Ks[2][8192];
  int hw = blockIdx.x;
  int swz = (hw & 7)*64 + (hw >> 3);
  int b = swz >> 8, ks = (swz >> 5) & 7, qt = swz & 31;
  int q0 = qt << 7;
  int t = threadIdx.x, w = t >> 6, lane = t & 63;
  int lq = lane & 15, g = lane >> 4;
  const uint4* Qb4 = (const uint4*)QKVb;
  const unsigned short* Kbp = QKVb + (size_t)NROWS*128;
  size_t rowbase = (size_t)b * 4096;
  int qrow = q0 + w*16;

  bf16x8 qf[4];
  #pragma unroll
  for (int f = 0; f < 4; ++f){
    uint4 v = Qb4[(rowbase + qrow + lq)*16 + 4*f + g];
    qf[f] = *(bf16x8*)&v;
  }
  int key0 = ks << 9;
  int krow = w*4 + (lane >> 4);
  int kcol16 = ((lane & 15) ^ (krow & 7)) << 4;
  const char* ksrc = (const char*)(Kbp + (rowbase + key0 + krow)*128) + kcol16;

  float m1 = -1e30f, m2 = -1e30f, s1 = 0.f, s2 = 0.f;
  int buf = 0;
  gload16(ksrc, Ks[0] + w*1024);
  __syncthreads();

  for (int it = 0; it < 16; ++it){
    if (it < 15) gload16(ksrc + (size_t)(it+1)*8192, Ks[buf^1] + w*1024);
    int xo = lq & 7;
    const char* kb = Ks[buf];
    bf16x8 kf[2][4];
    #pragma unroll
    for (int h = 0; h < 2; ++h)
      #pragma unroll
      for (int f = 0; f < 4; ++f)
        kf[h][f] = *(const bf16x8*)(kb + (h*16+lq)*256 + (((4*f+g) ^ xo) << 4));
    f32x4 S1[2], S2[2];
    #pragma unroll
    for (int h = 0; h < 2; ++h){
      f32x4 z1 = f32x4{0.f,0.f,0.f,0.f};
      z1 = MFMA16(kf[h][0], qf[0], z1);
      S1[h] = MFMA16(kf[h][1], qf[1], z1);
      f32x4 z2 = f32x4{0.f,0.f,0.f,0.f};
      z2 = MFMA16(kf[h][2], qf[2], z2);
      S2[h] = MFMA16(kf[h][3], qf[3], z2);
    }
    float t1 = fmaxf(fmaxf(fmaxf(S1[0][0],S1[0][1]), fmaxf(S1[0][2],S1[0][3])),
                     fmaxf(fmaxf(S1[1][0],S1[1][1]), fmaxf(S1[1][2],S1[1][3])));
    float t2 = fmaxf(fmaxf(fmaxf(S2[0][0],S2[0][1]), fmaxf(S2[0][2],S2[0][3])),
                     fmaxf(fmaxf(S2[1][0],S2[1][1]), fmaxf(S2[1][2],S2[1][3])));
    t1 = fmaxf(t1, __shfl_xor(t1, 16)); t1 = fmaxf(t1, __shfl_xor(t1, 32));
    t2 = fmaxf(t2, __shfl_xor(t2, 16)); t2 = fmaxf(t2, __shfl_xor(t2, 32));
    float mn1 = fmaxf(m1, t1), mn2 = fmaxf(m2, t2);
    float p1 = 0.f, p2 = 0.f;
    #pragma unroll
    for (int h = 0; h < 2; ++h)
      #pragma unroll
      for (int r = 0; r < 4; ++r){
        p1 += __expf(S1[h][r] - mn1);
        p2 += __expf(S2[h][r] - mn2);
      }
    p1 += __shfl_xor(p1, 16); p1 += __shfl_xor(p1, 32);
    p2 += __shfl_xor(p2, 16); p2 += __shfl_xor(p2, 32);
    s1 = s1 * __expf(m1 - mn1) + p1; m1 = mn1;
    s2 = s2 * __expf(m2 - mn2) + p2; m2 = mn2;
    __syncthreads();
    buf ^= 1;
  }
  if (lane < 16){
    float4* stats4 = (float4*)stats;
    stats4[(size_t)((b*8 + ks) << 12) + qrow + lq] = float4{m1, s1, m2, s2};
  }
}

// ---------------- pass B: merged-weight PV, single O accumulator ----------------
__global__ __launch_bounds__(512,4)
void k_attnB(const unsigned short* __restrict__ QKVb,
             const float* __restrict__ lq1, const float* __restrict__ lq2,
             const float* __restrict__ lk1, const float* __restrict__ lk2,
             const float* __restrict__ stats, float* __restrict__ p0,
             float* __restrict__ p7, float* __restrict__ unused){
  __shared__ __align__(16) char Ks[2][8192];
  __shared__ __align__(16) char Vs[2][8192];
  int hw = blockIdx.x;
  int swz = (hw & 7)*64 + (hw >> 3);
  int b = swz >> 8, ks = (swz >> 5) & 7, qt = swz & 31;
  int q0 = qt << 7;
  int t = threadIdx.x, w = t >> 6, lane = t & 63;
  int lq = lane & 15, g = lane >> 4;
  const uint4* Qb4 = (const uint4*)QKVb;
  const unsigned short* Kbp = QKVb + (size_t)NROWS*128;
  const unsigned short* Vbp = QKVb + (size_t)2*NROWS*128;
  size_t rowbase = (size_t)b * 4096;
  int qrow = q0 + w*16;

  float pp1 = lq1[lane]*lk1[lane], pp2 = lq2[lane]*lk2[lane];
  #pragma unroll
  for (int d = 1; d < 64; d <<= 1){ pp1 += __shfl_xor(pp1, d); pp2 += __shfl_xor(pp2, d); }
  float lam = __expf(pp1) - __expf(pp2) + 0.3555090675909693f;

  const float4* stats4 = (const float4*)stats;
  float M1 = -1e30f, M2 = -1e30f;
  float4 st[8];
  #pragma unroll
  for (int wu = 0; wu < 8; ++wu){
    st[wu] = stats4[(size_t)((b*8 + wu) << 12) + qrow + lq];
    M1 = fmaxf(M1, st[wu].x); M2 = fmaxf(M2, st[wu].z);
  }
  float L1 = 0.f, L2 = 0.f;
  #pragma unroll
  for (int wu = 0; wu < 8; ++wu){
    L1 += st[wu].y * __expf(st[wu].x - M1);
    L2 += st[wu].w * __expf(st[wu].z - M2);
  }
  float a1 = M1 + __logf(L1);
  float a2 = M2 + __logf(L2);

  bf16x8 qf[4];
  #pragma unroll
  for (int f = 0; f < 4; ++f){
    uint4 v = Qb4[(rowbase + qrow + lq)*16 + 4*f + g];
    qf[f] = *(bf16x8*)&v;
  }
  f32x4 O[8];
  #pragma unroll
  for (int dg = 0; dg < 8; ++dg) O[dg] = f32x4{0.f,0.f,0.f,0.f};

  int key0 = ks << 9;
  int krow = w*4 + (lane >> 4);
  int kcol16 = ((lane & 15) ^ (krow & 7)) << 4;
  const char* ksrc = (const char*)(Kbp + (rowbase + key0 + krow)*128) + kcol16;
  // V tr-subtile source (validated r1/r2), wave w stages d-slice dg=w
  int kl = 4*((lane >> 3) & 7) + ((lane >> 1) & 3);
  int dl = 8*(lane & 1);
  const char* vsrc = (const char*)(Vbp + (rowbase + key0 + kl)*128 + w*16 + dl);

  int buf = 0;
  gload16(ksrc, Ks[0] + w*1024);
  gload16(vsrc, Vs[0] + w*1024);
  __syncthreads();

  for (int it = 0; it < 16; ++it){
    if (it < 15){
      gload16(ksrc + (size_t)(it+1)*8192, Ks[buf^1] + w*1024);
      gload16(vsrc + (size_t)(it+1)*8192, Vs[buf^1] + w*1024);
    }
    int xo = lq & 7;
    const char* kb = Ks[buf];
    bf16x8 kf[2][4];
    #pragma unroll
    for (int h = 0; h < 2; ++h)
      #pragma unroll
      for (int f = 0; f < 4; ++f)
        kf[h][f] = *(const bf16x8*)(kb + (h*16+lq)*256 + (((4*f+g) ^ xo) << 4));
    f32x4 S1[2], S2[2];
    #pragma unroll
    for (int h = 0; h < 2; ++h){
      f32x4 z1 = f32x4{0.f,0.f,0.f,0.f};
      z1 = MFMA16(kf[h][0], qf[0], z1);
      S1[h] = MFMA16(kf[h][1], qf[1], z1);
      f32x4 z2 = f32x4{0.f,0.f,0.f,0.f};
      z2 = MFMA16(kf[h][2], qf[2], z2);
      S2[h] = MFMA16(kf[h][3], qf[3], z2);
    }
    bf16x8 P;
    #pragma unroll
    for (int h = 0; h < 2; ++h)
      #pragma unroll
      for (int r = 0; r < 4; ++r){
        float p = fmaf(-lam, __expf(S2[h][r] - a2), __expf(S1[h][r] - a1));
        P[h*4 + r] = (short)f2bf(p);
      }
    unsigned vb0 = (unsigned)(uintptr_t)&Vs[buf][0];
    unsigned long long tr0[4], tr1[4];
    #pragma unroll
    for (int dg = 0; dg < 4; ++dg){
      unsigned a = vb0 + dg*1024 + lane*8;
      asm volatile("ds_read_b64_tr_b16 %0, %2 offset:0\n\t"
                   "ds_read_b64_tr_b16 %1, %2 offset:512"
                   : "=&v"(tr0[dg]), "=&v"(tr1[dg]) : "v"(a) : "memory");
    }
    asm volatile("s_waitcnt lgkmcnt(0)" ::: "memory");
    __builtin_amdgcn_sched_barrier(0);
    #pragma unroll
    for (int dg = 0; dg < 4; ++dg){
      union { unsigned long long u[2]; bf16x8 v; } vv;
      vv.u[0] = tr0[dg]; vv.u[1] = tr1[dg];
      O[dg] = MFMA16(P, vv.v, O[dg]);
    }
    #pragma unroll
    for (int dg = 4; dg < 8; ++dg){
      unsigned a = vb0 + dg*1024 + lane*8;
      asm volatile("ds_read_b64_tr_b16 %0, %2 offset:0\n\t"
                   "ds_read_b64_tr_b16 %1, %2 offset:512"
                   : "=&v"(tr0[dg-4]), "=&v"(tr1[dg-4]) : "v"(a) : "memory");
    }
    asm volatile("s_waitcnt lgkmcnt(0)" ::: "memory");
    __builtin_amdgcn_sched_barrier(0);
    #pragma unroll
    for (int dg = 4; dg < 8; ++dg){
      union { unsigned long long u[2]; bf16x8 v; } vv;
      vv.u[0] = tr0[dg-4]; vv.u[1] = tr1[dg-4];
      O[dg] = MFMA16(P, vv.v, O[dg]);
    }
    __syncthreads();
    buf ^= 1;
  }

  float* opart = (ks < 7) ? (p0 + (size_t)ks*1048576) : p7;
  #pragma unroll
  for (int dg = 0; dg < 8; ++dg){
    #pragma unroll
    for (int r = 0; r < 4; ++r)
      opart[(size_t)(b*4096 + qrow + 4*g + r)*128 + dg*16 + lq] = O[dg][r];
  }
}

// ---------------- combine: out = sum over 8 key-split partials ----------------
__global__ void k_combine(const float4* __restrict__ p0, const float4* __restrict__ p7,
                          float4* __restrict__ out){
  int idx = blockIdx.x * 256 + threadIdx.x;   // 262,144
  float4 a = p0[idx];
  #pragma unroll
  for (int ks = 1; ks < 7; ++ks){
    float4 v = p0[(size_t)ks*262144 + idx];
    a.x += v.x; a.y += v.y; a.z += v.z; a.w += v.w;
  }
  float4 v = p7[idx];
  a.x += v.x; a.y += v.y; a.z += v.z; a.w += v.w;
  out[idx] = a;
}

extern "C" void kernel_launch(void* const* d_in, const int* in_sizes, int n_in,
                              void* d_out, int out_size, void* d_ws, size_t ws_size,
                              hipStream_t stream){
  const float* x   = (const float*)d_in[0];
  const float* Wq  = (const float*)d_in[1];
  const float* Wk  = (const float*)d_in[2];
  const float* Wv  = (const float*)d_in[3];
  const float* lq1 = (const float*)d_in[4];
  const float* lq2 = (const float*)d_in[5];
  const float* lk1 = (const float*)d_in[6];
  const float* lk2 = (const float*)d_in[7];
  float* out = (float*)d_out;
  char* ws = (char*)d_ws;

  unsigned short* xb    = (unsigned short*)(ws + XB_OFF);
  unsigned short* Wt    = (unsigned short*)(ws + WT_OFF);
  float*          QKVf  = (float*)(ws + QKVF_OFF);
  unsigned short* QKVb  = (unsigned short*)(ws + QKVB_OFF);
  float*          stats = (float*)(ws + STATS_OFF);
  float*          op0   = (float*)(ws + XB_OFF);
  float*          op7   = (float*)(ws + OP7_OFF);

  k_prep_x<<<dim3(4096), dim3(256), 0, stream>>>((const float4*)x, (uint4*)xb);
  k_prep_w<<<dim3(96), dim3(256), 0, stream>>>(Wq, Wk, Wv, Wt);
  k_gemm_qkv<<<dim3(768), dim3(256), 0, stream>>>(xb, Wt, QKVf);
  k_rope<<<dim3(2048), dim3(256), 0, stream>>>(QKVf, QKVb);
  k_stats<<<dim3(512), dim3(512), 0, stream>>>(QKVb, stats);
  k_attnB<<<dim3(512), dim3(512), 0, stream>>>(QKVb, lq1, lq2, lk1, lk2, stats, op0, op7, nullptr);
  k_combine<<<dim3(1024), dim3(256), 0, stream>>>((const float4*)op0, (const float4*)op7, (float4*)out);
}

// Round 10
// 154.417 us; speedup vs baseline: 1.7120x; 1.1252x over previous
//
#include <hip/hip_runtime.h>
#include <stdint.h>

typedef short bf16x8 __attribute__((ext_vector_type(8)));
typedef float f32x4 __attribute__((ext_vector_type(4)));

#define MFMA16(a,b,c) __builtin_amdgcn_mfma_f32_16x16x32_bf16((a),(b),(c),0,0,0)
#define EX2(x) __builtin_amdgcn_exp2f(x)

static __device__ __forceinline__ unsigned short f2bf(float f){
  union { float f; unsigned int u; } v; v.f = f;
  unsigned int r = (v.u + 0x7fffu + ((v.u >> 16) & 1u)) >> 16;
  return (unsigned short)r;
}

static __device__ __forceinline__ void gload16(const void* g, void* l){
  __builtin_amdgcn_global_load_lds((const __attribute__((address_space(1))) void*)g,
                                   (__attribute__((address_space(3))) void*)l, 16, 0, 0);
}

#define NROWS 8192
#define QSCALE 0.18033688011112042f   // 0.125 * log2(e)

// workspace byte offsets (d_ws is ~256MB; non-overlapping regions)
#define XB_OFF    0u            // 16 MB bf16 x
#define WT_OFF    16777216u     // 768 KB bf16 W^T
#define TAB_OFF   17825792u     // 2 MB  float2 sincos
#define QKVB_OFF  20971520u     // 6.3 MB bf16 Q,K,V
#define STATS_OFF 27262976u     // 512 KB float2 L1,L2 partials
#define OPART_OFF 29360128u     // 32 MB f32 O partials (8 x 4MB)

// ---------------- prep: x (fp32) -> xb (bf16) ----------------
__global__ void k_prep_x(const float4* __restrict__ x4, uint4* __restrict__ xb4){
  int idx = blockIdx.x * 256 + threadIdx.x;
  float4 a = x4[idx*2], b = x4[idx*2+1];
  uint4 o;
  o.x = (unsigned)f2bf(a.x) | ((unsigned)f2bf(a.y) << 16);
  o.y = (unsigned)f2bf(a.z) | ((unsigned)f2bf(a.w) << 16);
  o.z = (unsigned)f2bf(b.x) | ((unsigned)f2bf(b.y) << 16);
  o.w = (unsigned)f2bf(b.z) | ((unsigned)f2bf(b.w) << 16);
  xb4[idx] = o;
}

// ---------------- prep W: LDS transpose -> Wt[384][1024] bf16 ----------------
__global__ void k_prep_w(const float* __restrict__ Wq, const float* __restrict__ Wk,
                         const float* __restrict__ Wv, unsigned short* __restrict__ Wt){
  __shared__ float Wl[64][65];
  int bx = blockIdx.x;               // 96 = 6 n-tiles x 16 k-tiles
  int nt = bx / 16, kt = bx % 16;
  int n0 = nt*64, k0 = kt*64;
  int mat = n0 >> 7, nl0 = n0 & 127;
  const float* W = (mat == 0) ? Wq : (mat == 1 ? Wk : Wv);
  int t = threadIdx.x;
  int tr = t >> 4, tc = (t & 15) * 4;
  #pragma unroll
  for (int i = 0; i < 4; ++i){
    int kk = i*16 + tr;
    float4 v = *(const float4*)&W[(size_t)(k0+kk)*128 + nl0 + tc];
    Wl[kk][tc] = v.x; Wl[kk][tc+1] = v.y; Wl[kk][tc+2] = v.z; Wl[kk][tc+3] = v.w;
  }
  __syncthreads();
  int nn = t >> 2, kk0 = (t & 3) * 16;
  unsigned short tmp[16];
  #pragma unroll
  for (int j = 0; j < 16; ++j) tmp[j] = f2bf(Wl[kk0+j][nn]);
  *(uint4*)&Wt[(size_t)(n0+nn)*1024 + k0 + kk0]     = *(uint4*)&tmp[0];
  *(uint4*)&Wt[(size_t)(n0+nn)*1024 + k0 + kk0 + 8] = *(uint4*)&tmp[8];
}

// ---------------- sincos table: tab[s*64+i] = {cos, sin} ----------------
__global__ void k_sincos(float2* __restrict__ tab){
  int idx = blockIdx.x * 256 + threadIdx.x;   // 262,144
  int s = idx >> 6, i = idx & 63;
  double inv = exp((double)i * -0.14391156831212805);   // ln(10000)/64
  double rev = (double)s * inv * 0.15915494309189535;
  rev -= floor(rev);
  float fr = (float)rev;
  float cf, sf;
  asm("v_cos_f32 %0, %1" : "=v"(cf) : "v"(fr));
  asm("v_sin_f32 %0, %1" : "=v"(sf) : "v"(fr));
  tab[idx] = float2{cf, sf};
}

// ---------------- fused GEMM + RoPE + bf16: xb @ Wt^T -> QKVb ----------------
// BM=128 BN=128 BK=64, 512 thr (8 waves 2x4), dbuf, swizzled LDS, rope epilogue.
__global__ __launch_bounds__(512,4)
void k_gemm_rope(const unsigned short* __restrict__ xb,
                 const unsigned short* __restrict__ Wt,
                 const float2* __restrict__ tab,
                 unsigned short* __restrict__ QKVb){
  extern __shared__ __align__(16) char smem[];   // 66560 B
  int hw = blockIdx.x;
  int bx = (hw & 7)*24 + (hw >> 3);     // 192 = 8 x 24
  int mt = bx & 63, nt = bx >> 6;       // m-tile, matrix index
  int m0 = mt << 7;
  int t = threadIdx.x, lane = t & 63, w = t >> 6;
  int lq = lane & 15, g = lane >> 4;
  int wm = w >> 2, wc = w & 3;
  f32x4 acc[4][2];
  #pragma unroll
  for (int mi = 0; mi < 4; ++mi)
    #pragma unroll
    for (int ns = 0; ns < 2; ++ns) acc[mi][ns] = f32x4{0.f,0.f,0.f,0.f};

  // staging: row = i*64 + w*8 + (lane>>3), chunk' = (lane&7) ^ ((lane>>3)&7)
  int srow = w*8 + (lane >> 3);
  int schunk = ((lane & 7) ^ ((lane >> 3) & 7)) << 4;
  const char* asrc = (const char*)(xb + (size_t)(m0 + srow)*1024) + schunk;
  const char* bsrc = (const char*)(Wt + (size_t)(nt*128 + srow)*1024) + schunk;
  // per-row global byte stride = 2048; i adds 64 rows = 131072 B

  int buf = 0;
  #pragma unroll
  for (int i = 0; i < 2; ++i){
    gload16(asrc + (size_t)i*131072, smem + i*8192 + w*1024);
    gload16(bsrc + (size_t)i*131072, smem + 32768 + i*8192 + w*1024);
  }
  __syncthreads();

  int xo = lq & 7;
  for (int kk = 0; kk < 16; ++kk){
    if (kk < 15){
      size_t ko = (size_t)(kk+1)*128;   // 64 k * 2B
      char* an = smem + (buf^1)*16384;
      char* bn = smem + 32768 + (buf^1)*16384;
      #pragma unroll
      for (int i = 0; i < 2; ++i){
        gload16(asrc + ko + (size_t)i*131072, an + i*8192 + w*1024);
        gload16(bsrc + ko + (size_t)i*131072, bn + i*8192 + w*1024);
      }
    }
    const char* ac = smem + buf*16384;
    const char* bc = smem + 32768 + buf*16384;
    bf16x8 bfr[2][2];
    #pragma unroll
    for (int ns = 0; ns < 2; ++ns)
      #pragma unroll
      for (int ks = 0; ks < 2; ++ks)
        bfr[ns][ks] = *(const bf16x8*)(bc + (wc*32 + ns*16 + lq)*128 + (((ks*4+g) ^ xo) << 4));
    #pragma unroll
    for (int mi = 0; mi < 4; ++mi){
      bf16x8 afr[2];
      #pragma unroll
      for (int ks = 0; ks < 2; ++ks)
        afr[ks] = *(const bf16x8*)(ac + (wm*64 + mi*16 + lq)*128 + (((ks*4+g) ^ xo) << 4));
      #pragma unroll
      for (int ns = 0; ns < 2; ++ns)
        #pragma unroll
        for (int ks = 0; ks < 2; ++ks)
          acc[mi][ns] = MFMA16(afr[ks], bfr[ns][ks], acc[mi][ns]);
    }
    __syncthreads();
    buf ^= 1;
  }

  // epilogue: acc -> LDS f32 [128][130] -> rope -> bf16 global
  float* cbuf = (float*)smem;
  #pragma unroll
  for (int mi = 0; mi < 4; ++mi){
    int row = wm*64 + mi*16 + 4*g;
    #pragma unroll
    for (int ns = 0; ns < 2; ++ns){
      int col = wc*32 + ns*16 + lq;
      #pragma unroll
      for (int r = 0; r < 4; ++r)
        cbuf[(row + r)*130 + col] = acc[mi][ns][r];
    }
  }
  __syncthreads();
  int rr = t >> 2, cb = (t & 3) * 16;
  int grow = m0 + rr;
  int s = grow & 4095;
  const float2* tb = tab + s*64;
  unsigned short obuf[32];
  if (nt == 2){
    #pragma unroll
    for (int j = 0; j < 16; ++j){
      obuf[j]    = f2bf(cbuf[rr*130 + cb + j]);
      obuf[16+j] = f2bf(cbuf[rr*130 + cb + j + 64]);
    }
  } else {
    float sc = (nt == 0) ? QSCALE : 1.0f;
    #pragma unroll
    for (int j = 0; j < 16; ++j){
      float v1 = cbuf[rr*130 + cb + j];
      float v2 = cbuf[rr*130 + cb + j + 64];
      float2 cs = tb[cb + j];
      obuf[j]    = f2bf((v1*cs.x - v2*cs.y)*sc);
      obuf[16+j] = f2bf((v2*cs.x + v1*cs.y)*sc);
    }
  }
  unsigned short* dst = QKVb + (size_t)nt*NROWS*128 + (size_t)grow*128 + cb;
  *(uint4*)(dst)      = *(uint4*)&obuf[0];
  *(uint4*)(dst + 8)  = *(uint4*)&obuf[8];
  *(uint4*)(dst + 64) = *(uint4*)&obuf[16];
  *(uint4*)(dst + 72) = *(uint4*)&obuf[24];
}

// ---------------- pass A: denominators L1,L2 (log2 domain, no max) ----------------
// grid 512 = b(2) x ks(8) x qt(32); 8 waves x 16 q-rows; 512 keys, 8 steps of 64.
__global__ __launch_bounds__(512,4)
void k_stats(const unsigned short* __restrict__ QKVb, float2* __restrict__ stats){
  __shared__ __align__(16) char Ks[2][16384];
  int hw = blockIdx.x;
  int swz = (hw & 7)*64 + (hw >> 3);
  int b = swz >> 8, ks = (swz >> 5) & 7, qt = swz & 31;
  int t = threadIdx.x, w = t >> 6, lane = t & 63;
  int lq = lane & 15, g = lane >> 4;
  const uint4* Qb4 = (const uint4*)QKVb;
  const unsigned short* Kbp = QKVb + (size_t)NROWS*128;
  size_t rowbase = (size_t)b * 4096;
  int qrow = (qt << 7) + w*16;

  bf16x8 qf[4];
  #pragma unroll
  for (int f = 0; f < 4; ++f){
    uint4 v = Qb4[(rowbase + qrow + lq)*16 + 4*f + g];
    qf[f] = *(bf16x8*)&v;
  }
  int key0 = ks << 9;
  int kr0 = w*8 + (lane >> 4);
  int c0 = ((lane & 15) ^ (kr0 & 7)) << 4;
  int c1 = ((lane & 15) ^ ((kr0 + 4) & 7)) << 4;
  const char* ksrc0 = (const char*)(Kbp + (rowbase + key0 + kr0)*128) + c0;
  const char* ksrc1 = (const char*)(Kbp + (rowbase + key0 + kr0 + 4)*128) + c1;

  f32x4 sv1 = f32x4{0.f,0.f,0.f,0.f}, sv2 = f32x4{0.f,0.f,0.f,0.f};
  int buf = 0;
  gload16(ksrc0, Ks[0] + w*2048);
  gload16(ksrc1, Ks[0] + w*2048 + 1024);
  __syncthreads();
  int xo = lq & 7;

  for (int it = 0; it < 8; ++it){
    if (it < 7){
      size_t ko = (size_t)(it+1)*16384;
      gload16(ksrc0 + ko, Ks[buf^1] + w*2048);
      gload16(ksrc1 + ko, Ks[buf^1] + w*2048 + 1024);
    }
    const char* kb = Ks[buf];
    #pragma unroll
    for (int kg = 0; kg < 2; ++kg){
      #pragma unroll
      for (int h = 0; h < 2; ++h){
        const char* krow = kb + (kg*32 + h*16 + lq)*256;
        bf16x8 k0 = *(const bf16x8*)(krow + (((0+g) ^ xo) << 4));
        bf16x8 k1 = *(const bf16x8*)(krow + (((4+g) ^ xo) << 4));
        bf16x8 k2 = *(const bf16x8*)(krow + (((8+g) ^ xo) << 4));
        bf16x8 k3 = *(const bf16x8*)(krow + (((12+g) ^ xo) << 4));
        f32x4 z = f32x4{0.f,0.f,0.f,0.f};
        z = MFMA16(k0, qf[0], z);
        f32x4 S1 = MFMA16(k1, qf[1], z);
        z = f32x4{0.f,0.f,0.f,0.f};
        z = MFMA16(k2, qf[2], z);
        f32x4 S2 = MFMA16(k3, qf[3], z);
        #pragma unroll
        for (int r = 0; r < 4; ++r){
          sv1[r] += EX2(S1[r]);
          sv2[r] += EX2(S2[r]);
        }
      }
    }
    __syncthreads();
    buf ^= 1;
  }
  float s1 = sv1[0]+sv1[1]+sv1[2]+sv1[3];
  float s2 = sv2[0]+sv2[1]+sv2[2]+sv2[3];
  s1 += __shfl_xor(s1, 16); s1 += __shfl_xor(s1, 32);
  s2 += __shfl_xor(s2, 16); s2 += __shfl_xor(s2, 32);
  if (lane < 16)
    stats[(size_t)(b*8 + ks)*4096 + qrow + lq] = float2{s1, s2};
}

// ---------------- pass B: merged-weight PV ----------------
__global__ __launch_bounds__(512,4)
void k_attnB(const unsigned short* __restrict__ QKVb,
             const float* __restrict__ lq1, const float* __restrict__ lq2,
             const float* __restrict__ lk1, const float* __restrict__ lk2,
             const float2* __restrict__ stats, float* __restrict__ opart){
  __shared__ __align__(16) char Ks[2][16384];
  __shared__ __align__(16) char Vs[2][16384];
  int hw = blockIdx.x;
  int swz = (hw & 7)*64 + (hw >> 3);
  int b = swz >> 8, ks = (swz >> 5) & 7, qt = swz & 31;
  int t = threadIdx.x, w = t >> 6, lane = t & 63;
  int lq = lane & 15, g = lane >> 4;
  const uint4* Qb4 = (const uint4*)QKVb;
  const unsigned short* Kbp = QKVb + (size_t)NROWS*128;
  const unsigned short* Vbp = QKVb + (size_t)2*NROWS*128;
  size_t rowbase = (size_t)b * 4096;
  int qrow = (qt << 7) + w*16;

  float pp1 = lq1[lane]*lk1[lane], pp2 = lq2[lane]*lk2[lane];
  #pragma unroll
  for (int d = 1; d < 64; d <<= 1){ pp1 += __shfl_xor(pp1, d); pp2 += __shfl_xor(pp2, d); }
  float lam = __expf(pp1) - __expf(pp2) + 0.3555090675909693f;

  float L1 = 0.f, L2 = 0.f;
  #pragma unroll
  for (int wu = 0; wu < 8; ++wu){
    float2 st = stats[(size_t)(b*8 + wu)*4096 + qrow + lq];
    L1 += st.x; L2 += st.y;
  }
  float a1 = __builtin_amdgcn_logf(L1);
  float a2 = __builtin_amdgcn_logf(L2);
  f32x4 i1, i2;
  #pragma unroll
  for (int r = 0; r < 4; ++r){ i1[r] = -a1; i2[r] = -a2; }

  bf16x8 qf[4];
  #pragma unroll
  for (int f = 0; f < 4; ++f){
    uint4 v = Qb4[(rowbase + qrow + lq)*16 + 4*f + g];
    qf[f] = *(bf16x8*)&v;
  }
  f32x4 O[8];
  #pragma unroll
  for (int dg = 0; dg < 8; ++dg) O[dg] = f32x4{0.f,0.f,0.f,0.f};

  int key0 = ks << 9;
  int kr0 = w*8 + (lane >> 4);
  int c0 = ((lane & 15) ^ (kr0 & 7)) << 4;
  int c1 = ((lane & 15) ^ ((kr0 + 4) & 7)) << 4;
  const char* ksrc0 = (const char*)(Kbp + (rowbase + key0 + kr0)*128) + c0;
  const char* ksrc1 = (const char*)(Kbp + (rowbase + key0 + kr0 + 4)*128) + c1;
  // V tr-subtile source: within 32-key chunk, lane -> (k, d) per validated layout
  int kl = 4*((lane >> 3) & 7) + ((lane >> 1) & 3);
  int dl = 8*(lane & 1);
  const char* vsrc = (const char*)(Vbp + (rowbase + key0 + kl)*128 + w*16 + dl);

  int buf = 0;
  gload16(ksrc0, Ks[0] + w*2048);
  gload16(ksrc1, Ks[0] + w*2048 + 1024);
  gload16(vsrc,        Vs[0] + w*1024);
  gload16(vsrc + 8192, Vs[0] + 8192 + w*1024);
  __syncthreads();
  int xo = lq & 7;

  for (int it = 0; it < 8; ++it){
    if (it < 7){
      size_t ko = (size_t)(it+1)*16384;
      gload16(ksrc0 + ko, Ks[buf^1] + w*2048);
      gload16(ksrc1 + ko, Ks[buf^1] + w*2048 + 1024);
      gload16(vsrc + ko,        Vs[buf^1] + w*1024);
      gload16(vsrc + ko + 8192, Vs[buf^1] + 8192 + w*1024);
    }
    const char* kb = Ks[buf];
    bf16x8 P[2];
    #pragma unroll
    for (int kg = 0; kg < 2; ++kg){
      f32x4 S1[2], S2[2];
      #pragma unroll
      for (int h = 0; h < 2; ++h){
        const char* krow = kb + (kg*32 + h*16 + lq)*256;
        bf16x8 k0 = *(const bf16x8*)(krow + (((0+g) ^ xo) << 4));
        bf16x8 k1 = *(const bf16x8*)(krow + (((4+g) ^ xo) << 4));
        bf16x8 k2 = *(const bf16x8*)(krow + (((8+g) ^ xo) << 4));
        bf16x8 k3 = *(const bf16x8*)(krow + (((12+g) ^ xo) << 4));
        f32x4 z = MFMA16(k0, qf[0], i1);
        S1[h] = MFMA16(k1, qf[1], z);
        z = MFMA16(k2, qf[2], i2);
        S2[h] = MFMA16(k3, qf[3], z);
      }
      #pragma unroll
      for (int h = 0; h < 2; ++h)
        #pragma unroll
        for (int r = 0; r < 4; ++r){
          float p = fmaf(-lam, EX2(S2[h][r]), EX2(S1[h][r]));
          P[kg][h*4 + r] = (short)f2bf(p);
        }
    }
    // PV: 2 key-groups x 8 d-groups, tr-reads from Vs
    #pragma unroll
    for (int kg = 0; kg < 2; ++kg){
      unsigned vb0 = (unsigned)(uintptr_t)&Vs[buf][kg*8192];
      unsigned long long tr0[4], tr1[4];
      #pragma unroll
      for (int half = 0; half < 2; ++half){
        #pragma unroll
        for (int dg = 0; dg < 4; ++dg){
          unsigned a = vb0 + (half*4 + dg)*1024 + lane*8;
          asm volatile("ds_read_b64_tr_b16 %0, %2 offset:0\n\t"
                       "ds_read_b64_tr_b16 %1, %2 offset:512"
                       : "=&v"(tr0[dg]), "=&v"(tr1[dg]) : "v"(a) : "memory");
        }
        asm volatile("s_waitcnt lgkmcnt(0)" ::: "memory");
        __builtin_amdgcn_sched_barrier(0);
        #pragma unroll
        for (int dg = 0; dg < 4; ++dg){
          union { unsigned long long u[2]; bf16x8 v; } vv;
          vv.u[0] = tr0[dg]; vv.u[1] = tr1[dg];
          O[half*4 + dg] = MFMA16(P[kg], vv.v, O[half*4 + dg]);
        }
      }
    }
    __syncthreads();
    buf ^= 1;
  }

  float* op = opart + (size_t)ks*1048576;
  #pragma unroll
  for (int dg = 0; dg < 8; ++dg){
    #pragma unroll
    for (int r = 0; r < 4; ++r)
      op[(size_t)(b*4096 + qrow + 4*g + r)*128 + dg*16 + lq] = O[dg][r];
  }
}

// ---------------- combine: out = sum over 8 key-split partials ----------------
__global__ void k_combine(const float4* __restrict__ op, float4* __restrict__ out){
  int idx = blockIdx.x * 256 + threadIdx.x;   // 262,144
  float4 a = op[idx];
  #pragma unroll
  for (int ksl = 1; ksl < 8; ++ksl){
    float4 v = op[(size_t)ksl*262144 + idx];
    a.x += v.x; a.y += v.y; a.z += v.z; a.w += v.w;
  }
  out[idx] = a;
}

extern "C" void kernel_launch(void* const* d_in, const int* in_sizes, int n_in,
                              void* d_out, int out_size, void* d_ws, size_t ws_size,
                              hipStream_t stream){
  const float* x   = (const float*)d_in[0];
  const float* Wq  = (const float*)d_in[1];
  const float* Wk  = (const float*)d_in[2];
  const float* Wv  = (const float*)d_in[3];
  const float* lq1 = (const float*)d_in[4];
  const float* lq2 = (const float*)d_in[5];
  const float* lk1 = (const float*)d_in[6];
  const float* lk2 = (const float*)d_in[7];
  float* out = (float*)d_out;
  char* ws = (char*)d_ws;

  unsigned short* xb    = (unsigned short*)(ws + XB_OFF);
  unsigned short* Wt    = (unsigned short*)(ws + WT_OFF);
  float2*         tab   = (float2*)(ws + TAB_OFF);
  unsigned short* QKVb  = (unsigned short*)(ws + QKVB_OFF);
  float2*         stats = (float2*)(ws + STATS_OFF);
  float*          opart = (float*)(ws + OPART_OFF);

  k_prep_x<<<dim3(4096), dim3(256), 0, stream>>>((const float4*)x, (uint4*)xb);
  k_prep_w<<<dim3(96), dim3(256), 0, stream>>>(Wq, Wk, Wv, Wt);
  k_sincos<<<dim3(1024), dim3(256), 0, stream>>>(tab);
  k_gemm_rope<<<dim3(192), dim3(512), 66560, stream>>>(xb, Wt, tab, QKVb);
  k_stats<<<dim3(512), dim3(512), 0, stream>>>(QKVb, stats);
  k_attnB<<<dim3(512), dim3(512), 0, stream>>>(QKVb, lq1, lq2, lk1, lk2, stats, opart);
  k_combine<<<dim3(1024), dim3(256), 0, stream>>>((const float4*)opart, (float4*)out);
}